// Round 13
// baseline (122.228 us; speedup 1.0000x reference)
//
#include <hip/hip_runtime.h>

#define NN    2048   // nodes per sample
#define KNN   16     // neighbors
#define BATCH 8

__device__ __forceinline__ unsigned umin_u(unsigned a, unsigned b) { return a < b ? a : b; }

// ---------------------------------------------------------------------------
// cross-lane helpers
// ---------------------------------------------------------------------------
__device__ __forceinline__ unsigned long long bcast64(unsigned long long v, int l) {
  unsigned lo = __builtin_amdgcn_readlane((unsigned)(v & 0xffffffffu), l);
  unsigned hi = __builtin_amdgcn_readlane((unsigned)(v >> 32), l);
  return ((unsigned long long)hi << 32) | lo;
}

// per-16-lane-row shift up by 1 (lane l <- lane l-1), lane 0 of each row -> 0.
__device__ __forceinline__ unsigned long long dpp_shr1_zero(unsigned long long v) {
  int lo = __builtin_amdgcn_update_dpp(0, (int)(unsigned)(v & 0xffffffffu), 0x111, 0xf, 0xf, true);
  int hi = __builtin_amdgcn_update_dpp(0, (int)(unsigned)(v >> 32),        0x111, 0xf, 0xf, true);
  return ((unsigned long long)(unsigned)hi << 32) | (unsigned)lo;
}

// ---------------------------------------------------------------------------
// Kernel 1: exact kNN (K=16), one WAVE per node, 8 waves/block, fused GCN L1.
// (unchanged from R12 — occupancy-first, no key cache; tau+64ulp threshold,
// branchless DPP insert, unseeded-rerun insurance, clamped indices.)
// ---------------------------------------------------------------------------
__global__ __launch_bounds__(512) void knn_l1_kernel(const float* __restrict__ coords,
                                                     const float* __restrict__ W1,
                                                     const float* __restrict__ b1,
                                                     int* __restrict__ nbr,
                                                     float* __restrict__ x1) {
  __shared__ float4 sP[NN];  // -2x,-2y,-2z,|p|^2  (32 KB)

  const int b        = blockIdx.x >> 8;          // 256 blocks per sample
  const int nodeBase = (blockIdx.x & 255) << 3;  // 8 nodes per block
  const int lane     = (int)threadIdx.x & 63;
  const int wid      = (int)threadIdx.x >> 6;

  const float* cb = coords + (size_t)b * NN * 6;
  for (int p = threadIdx.x; p < NN; p += 512) {
    const float2 v01 = *reinterpret_cast<const float2*>(cb + p * 6);
    const float2 v23 = *reinterpret_cast<const float2*>(cb + p * 6 + 2);
    const float x = v01.x, y = v01.y, z = v23.x;
    float4 v; v.x = -2.0f * x; v.y = -2.0f * y; v.z = -2.0f * z;
    v.w = x * x + y * y + z * z;
    sP[p] = v;
  }
  __syncthreads();

  const int i = nodeBase + wid;
  const float4 pi = sP[i];
  const float xi = pi.x * -0.5f, yi = pi.y * -0.5f, zi = pi.z * -0.5f;
  const float base = pi.w + 1.0f;   // +1 keeps d2' strictly positive

  // ---- pass 1: per-lane min key over this lane's 32 candidates ----
  unsigned lmin = 0xFFFFFFFFu;
  for (int t0 = 0; t0 < NN; t0 += 64) {
    const float4 pj = sP[t0 + lane];
    const float d2 = fmaf(pj.x, xi, fmaf(pj.y, yi, fmaf(pj.z, zi, pj.w + base)));
    lmin = umin_u(lmin, __float_as_uint(d2));   // positive => bits monotonic
  }

  // exact 17th-smallest of the 64 lane-minima (self occupies at most one rank)
  unsigned tau = 0u;
  for (int bit = 31; bit >= 0; --bit) {
    const unsigned t_try = tau + ((1u << bit) - 1u);
    const unsigned long long m = __ballot(lmin <= t_try);
    if (__popcll(m) < 17) tau += (1u << bit);
  }
  // +64 ulp slack: covers any pass-1/pass-2 contraction drift (R6-proven)
  const unsigned tau_s = (tau >= 0xFFFFFFC0u) ? 0xFFFFFFFFu : tau + 64u;

  // ---- pass 2: recompute keys, ballot vs constant threshold, insert all ----
  unsigned long long lk = ~0ull;   // lane k (k<16): k-th smallest so far
  unsigned thr = tau_s;

  for (int attempt = 0; attempt < 2; ++attempt) {
    for (int t0 = 0; t0 < NN; t0 += 64) {
      const int j = t0 + lane;
      const float4 pj = sP[j];
      const float d2 = fmaf(pj.x, xi, fmaf(pj.y, yi, fmaf(pj.z, zi, pj.w + base)));
      const unsigned k32 = __float_as_uint(d2);
      unsigned long long mask = __ballot(k32 <= thr && j != i);
      while (mask) {
        const int src = __ffsll((unsigned long long)mask) - 1;
        mask &= mask - 1;
        const unsigned ckey = __builtin_amdgcn_readlane(k32, src);  // lazy pack
        const unsigned long long c =
            ((unsigned long long)ckey << 32) | (unsigned)(t0 + src);
        const unsigned long long pk = dpp_shr1_zero(lk);      // row shift-up
        const unsigned long long mx = (pk > c) ? pk : c;
        lk = (lk < mx) ? lk : mx;                             // sorted insert
      }
    }
    if (bcast64(lk, 15) != ~0ull) break;  // >=16 entries (slack makes this sure)
    lk = ~0ull; thr = 0xFFFFFFFFu;        // insurance: exact unseeded rerun
  }

  // clamped index: a sentinel can never reach memory
  const int nj = (int)umin_u((unsigned)(lk & 0xffffffffu), NN - 1u);
  if (lane < KNN) {
    nbr[((size_t)b * NN + i) * KNN + lane] = nj;
  }

  // ---- fused GCN layer 1: x1[i] = relu( ((sum_nbr c + c_i)/17) @ W1 + b1 ) ----
  float r[6];
#pragma unroll
  for (int c = 0; c < 6; ++c) r[c] = 0.f;
  if (lane < KNN) {
    const float* row = cb + (size_t)nj * 6;
    const float2 a = *reinterpret_cast<const float2*>(row);
    const float2 m = *reinterpret_cast<const float2*>(row + 2);
    const float2 q = *reinterpret_cast<const float2*>(row + 4);
    r[0] = a.x; r[1] = a.y; r[2] = m.x; r[3] = m.y; r[4] = q.x; r[5] = q.y;
  }
#pragma unroll
  for (int m = 1; m <= 8; m <<= 1) {
#pragma unroll
    for (int c = 0; c < 6; ++c) r[c] += __shfl_xor(r[c], m);
  }
  const float* self = cb + (size_t)i * 6;
  float agg[6];
#pragma unroll
  for (int c = 0; c < 6; ++c) {
    const float nbs = __uint_as_float(__builtin_amdgcn_readfirstlane(__float_as_uint(r[c])));
    agg[c] = (nbs + self[c]) * (1.0f / 17.0f);
  }
  float acc = b1[lane];
#pragma unroll
  for (int c = 0; c < 6; ++c) acc = fmaf(agg[c], W1[c * 64 + lane], acc);
  x1[((size_t)b * NN + i) * 64 + lane] = fmaxf(acc, 0.f);
}

// ---------------------------------------------------------------------------
// Kernel 2: fused GCN layer 2 + final Linear, register-tiled.
// W-TRAFFIC-FIRST retile (R12 post-mortem: phase B/C are L1-W-traffic-bound,
// 768 KB/block at 4-node reuse ~ 10-12us floor): thread = 8 nodes x 4 outputs,
// 128 threads / 32-node tile / 512 blocks -> 4 node-groups x 96 KB = 384 KB
// per block, total W traffic halved (393 -> 197 MB). 27.6 KB LDS; 4 waves/CU
// still saturates the L1 port (traffic-bound, not latency-bound).
// XCD swizzle unchanged (512 = 8 x 64, sample-per-XCD).
// ---------------------------------------------------------------------------
__global__ __launch_bounds__(128) void layers_kernel(const float* __restrict__ x1,
                                                     const int* __restrict__ nbr,
                                                     const float* __restrict__ W2,
                                                     const float* __restrict__ b2,
                                                     const float* __restrict__ Wf,
                                                     const float* __restrict__ bf,
                                                     float* __restrict__ out) {
  __shared__ float sA[32][68];    // aggregated x1 (pad 4)
  __shared__ float sB[32][132];   // x2 tile      (pad 4)
  __shared__ int   sN[512];

  const int t   = (int)threadIdx.x;
  const int bid = (int)blockIdx.x;
  // XCD swizzle: XCD k (= bid%8) exclusively processes sample k's 64 tiles
  const int swz = (bid & 7) * 64 + (bid >> 3);
  const int nodeBase = swz * 32;
  const int bs       = nodeBase >> 11;          // sample index (32 | 2048)

  // neighbor lists for 32 nodes (clamped: sentinel can never reach memory)
#pragma unroll
  for (int q = 0; q < 4; ++q)
    sN[t + q * 128] = (int)umin_u((unsigned)nbr[(size_t)nodeBase * KNN + t + q * 128], NN - 1u);
  __syncthreads();

  // Phase A: gather-aggregate x1 (thread = node t>>2, dims (t&3)*16 .. +15)
  {
    const int ln = t >> 2;
    const int d0 = (t & 3) * 16;
    const int n  = nodeBase + ln;
    const float* Xb = x1 + (((size_t)bs) << 11) * 64;
    const float* xn = x1 + (size_t)n * 64 + d0;
    float4 s0 = *reinterpret_cast<const float4*>(xn);
    float4 s1 = *reinterpret_cast<const float4*>(xn + 4);
    float4 s2 = *reinterpret_cast<const float4*>(xn + 8);
    float4 s3 = *reinterpret_cast<const float4*>(xn + 12);
    const int* nb = &sN[ln * 16];
#pragma unroll
    for (int k = 0; k < KNN; ++k) {
      const float* row = Xb + (size_t)nb[k] * 64 + d0;
      const float4 v0 = *reinterpret_cast<const float4*>(row);
      const float4 v1 = *reinterpret_cast<const float4*>(row + 4);
      const float4 v2 = *reinterpret_cast<const float4*>(row + 8);
      const float4 v3 = *reinterpret_cast<const float4*>(row + 12);
      s0.x += v0.x; s0.y += v0.y; s0.z += v0.z; s0.w += v0.w;
      s1.x += v1.x; s1.y += v1.y; s1.z += v1.z; s1.w += v1.w;
      s2.x += v2.x; s2.y += v2.y; s2.z += v2.z; s2.w += v2.w;
      s3.x += v3.x; s3.y += v3.y; s3.z += v3.z; s3.w += v3.w;
    }
    const float sc = 1.0f / 17.0f;
    float* dst = &sA[ln][d0];
    dst[0]  = s0.x * sc; dst[1]  = s0.y * sc; dst[2]  = s0.z * sc; dst[3]  = s0.w * sc;
    dst[4]  = s1.x * sc; dst[5]  = s1.y * sc; dst[6]  = s1.z * sc; dst[7]  = s1.w * sc;
    dst[8]  = s2.x * sc; dst[9]  = s2.y * sc; dst[10] = s2.z * sc; dst[11] = s2.w * sc;
    dst[12] = s3.x * sc; dst[13] = s3.y * sc; dst[14] = s3.z * sc; dst[15] = s3.w * sc;
  }
  __syncthreads();

  const int ng = (t >> 5) * 8;   // first of 8 nodes (4 groups x 8 = 32)
  const int o4 = (t & 31) * 4;   // 4 outputs

  // Phase B: x2 = relu(sA @ W2 + b2) -> sB  (K=64)
  {
    const float4 bv = *reinterpret_cast<const float4*>(b2 + o4);
    float4 a0 = bv, a1 = bv, a2 = bv, a3 = bv, a4 = bv, a5 = bv, a6 = bv, a7 = bv;
#pragma unroll 4
    for (int c = 0; c < 64; ++c) {
      const float4 w = *reinterpret_cast<const float4*>(W2 + (size_t)c * 128 + o4);
#define STEP(q, acc) { const float a = sA[ng + q][c];                         \
      acc.x += a * w.x; acc.y += a * w.y; acc.z += a * w.z; acc.w += a * w.w; }
      STEP(0, a0) STEP(1, a1) STEP(2, a2) STEP(3, a3)
      STEP(4, a4) STEP(5, a5) STEP(6, a6) STEP(7, a7)
#undef STEP
    }
#define STORE(q, acc) { float* d = &sB[ng + q][o4];                           \
    d[0] = fmaxf(acc.x, 0.f); d[1] = fmaxf(acc.y, 0.f);                       \
    d[2] = fmaxf(acc.z, 0.f); d[3] = fmaxf(acc.w, 0.f); }
    STORE(0, a0) STORE(1, a1) STORE(2, a2) STORE(3, a3)
    STORE(4, a4) STORE(5, a5) STORE(6, a6) STORE(7, a7)
#undef STORE
  }
  __syncthreads();

  // Phase C: out = sB @ Wf + bf  (K=128)
  {
    const float4 bv = *reinterpret_cast<const float4*>(bf + o4);
    float4 a0 = bv, a1 = bv, a2 = bv, a3 = bv, a4 = bv, a5 = bv, a6 = bv, a7 = bv;
#pragma unroll 4
    for (int c = 0; c < 128; ++c) {
      const float4 w = *reinterpret_cast<const float4*>(Wf + (size_t)c * 128 + o4);
#define STEP(q, acc) { const float a = sB[ng + q][c];                         \
      acc.x += a * w.x; acc.y += a * w.y; acc.z += a * w.z; acc.w += a * w.w; }
      STEP(0, a0) STEP(1, a1) STEP(2, a2) STEP(3, a3)
      STEP(4, a4) STEP(5, a5) STEP(6, a6) STEP(7, a7)
#undef STEP
    }
    float* o0 = out + (size_t)(nodeBase + ng) * 128 + o4;
    *reinterpret_cast<float4*>(o0)       = a0;
    *reinterpret_cast<float4*>(o0 + 128) = a1;
    *reinterpret_cast<float4*>(o0 + 256) = a2;
    *reinterpret_cast<float4*>(o0 + 384) = a3;
    *reinterpret_cast<float4*>(o0 + 512) = a4;
    *reinterpret_cast<float4*>(o0 + 640) = a5;
    *reinterpret_cast<float4*>(o0 + 768) = a6;
    *reinterpret_cast<float4*>(o0 + 896) = a7;
  }
}

// ---------------------------------------------------------------------------
extern "C" void kernel_launch(void* const* d_in, const int* in_sizes, int n_in,
                              void* d_out, int out_size, void* d_ws, size_t ws_size,
                              hipStream_t stream) {
  const float* coords = (const float*)d_in[0];
  const float* W1 = (const float*)d_in[1];
  const float* b1 = (const float*)d_in[2];
  const float* W2 = (const float*)d_in[3];
  const float* b2 = (const float*)d_in[4];
  const float* Wf = (const float*)d_in[5];
  const float* bf = (const float*)d_in[6];
  float* out = (float*)d_out;

  char* ws = (char*)d_ws;
  int*   nbr = (int*)ws;                              // 1 MB
  float* x1  = (float*)(ws + (size_t)(1u << 20) * 1); // 4 MB

  // kNN + layer 1: one wave per node, 8 waves/block
  knn_l1_kernel<<<BATCH * (NN / 8), 512, 0, stream>>>(coords, W1, b1, nbr, x1);

  // layer 2 (aggregate + 64->128 + relu) fused with final 128->128 linear
  layers_kernel<<<(BATCH * NN) / 32, 128, 0, stream>>>(x1, nbr, W2, b2, Wf, bf, out);
}

// Round 14
// 110.812 us; speedup vs baseline: 1.1030x; 1.1030x over previous
//
#include <hip/hip_runtime.h>

#define NN    2048   // nodes per sample
#define KNN   16     // neighbors
#define BATCH 8

__device__ __forceinline__ unsigned umin_u(unsigned a, unsigned b) { return a < b ? a : b; }

// ---------------------------------------------------------------------------
// cross-lane helpers
// ---------------------------------------------------------------------------
__device__ __forceinline__ unsigned long long bcast64(unsigned long long v, int l) {
  unsigned lo = __builtin_amdgcn_readlane((unsigned)(v & 0xffffffffu), l);
  unsigned hi = __builtin_amdgcn_readlane((unsigned)(v >> 32), l);
  return ((unsigned long long)hi << 32) | lo;
}

// per-16-lane-row shift up by 1 (lane l <- lane l-1), lane 0 of each row -> 0.
__device__ __forceinline__ unsigned long long dpp_shr1_zero(unsigned long long v) {
  int lo = __builtin_amdgcn_update_dpp(0, (int)(unsigned)(v & 0xffffffffu), 0x111, 0xf, 0xf, true);
  int hi = __builtin_amdgcn_update_dpp(0, (int)(unsigned)(v >> 32),        0x111, 0xf, 0xf, true);
  return ((unsigned long long)(unsigned)hi << 32) | (unsigned)lo;
}

// ---------------------------------------------------------------------------
// Kernel 1: exact kNN (K=16), one WAVE per node, 8 waves/block, fused GCN L1.
// (R11 configuration — best measured.) sP holds (-2x,-2y,-2z,|p|^2);
// d2' = fma chain + (sqi+sqj+1) > 0 so raw bits are the monotonic key
// (5 VALU/candidate). Keys cached in registers (single distance pass).
// tau = exact 17th-smallest of the 64 lane-minima (rank 17 absorbs self).
// Selection ballots against constant tau over the CACHED keys (bitwise
// identical to pass 1 — no drift hazard); branchless DPP sorted insert;
// lazy 64-bit pack via readlane only on insert. Unseeded rerun insurance;
// gathered indices clamped.
// ---------------------------------------------------------------------------
__global__ __launch_bounds__(512) void knn_l1_kernel(const float* __restrict__ coords,
                                                     const float* __restrict__ W1,
                                                     const float* __restrict__ b1,
                                                     int* __restrict__ nbr,
                                                     float* __restrict__ x1) {
  __shared__ float4 sP[NN];  // -2x,-2y,-2z,|p|^2  (32 KB)

  const int b        = blockIdx.x >> 8;          // 256 blocks per sample
  const int nodeBase = (blockIdx.x & 255) << 3;  // 8 nodes per block
  const int lane     = (int)threadIdx.x & 63;
  const int wid      = (int)threadIdx.x >> 6;

  const float* cb = coords + (size_t)b * NN * 6;
  for (int p = threadIdx.x; p < NN; p += 512) {
    const float2 v01 = *reinterpret_cast<const float2*>(cb + p * 6);
    const float2 v23 = *reinterpret_cast<const float2*>(cb + p * 6 + 2);
    const float x = v01.x, y = v01.y, z = v23.x;
    float4 v; v.x = -2.0f * x; v.y = -2.0f * y; v.z = -2.0f * z;
    v.w = x * x + y * y + z * z;
    sP[p] = v;
  }
  __syncthreads();

  const int i = nodeBase + wid;
  const float4 pi = sP[i];
  const float xi = pi.x * -0.5f, yi = pi.y * -0.5f, zi = pi.z * -0.5f;
  const float base = pi.w + 1.0f;   // +1 keeps d2' strictly positive

  // ---- single distance pass: cache 32 positive-key bits, track lane min ----
  unsigned key[32];          // static indices only -> stays in VGPRs
  unsigned lmin = 0xFFFFFFFFu;
#pragma unroll
  for (int it = 0; it < 32; ++it) {
    const float4 pj = sP[(it << 6) + lane];
    const float d2 = fmaf(pj.x, xi, fmaf(pj.y, yi, fmaf(pj.z, zi, pj.w + base)));
    const unsigned k32 = __float_as_uint(d2);   // positive => bits monotonic
    key[it] = k32;
    lmin = umin_u(lmin, k32);
  }

  // exact 17th-smallest of the 64 lane-minima (self occupies one rank at most)
  unsigned tau = 0u;
  for (int bit = 31; bit >= 0; --bit) {
    const unsigned t_try = tau + ((1u << bit) - 1u);
    const unsigned long long m = __ballot(lmin <= t_try);
    if (__popcll(m) < 17) tau += (1u << bit);
  }

  // ---- selection over cached keys: constant-tau ballot, branchless insert --
  unsigned long long lk = ~0ull;   // lane k (k<16): k-th smallest so far
  unsigned thr = tau;

  for (int attempt = 0; attempt < 2; ++attempt) {
#pragma unroll
    for (int it = 0; it < 32; ++it) {
      const int j = (it << 6) + lane;
      unsigned long long mask = __ballot(key[it] <= thr && j != i);
      while (mask) {
        const int src = __ffsll((unsigned long long)mask) - 1;
        mask &= mask - 1;
        const unsigned ckey = __builtin_amdgcn_readlane(key[it], src);  // lazy pack
        const unsigned long long c =
            ((unsigned long long)ckey << 32) | (unsigned)((it << 6) + src);
        const unsigned long long pk = dpp_shr1_zero(lk);      // row shift-up
        const unsigned long long mx = (pk > c) ? pk : c;
        lk = (lk < mx) ? lk : mx;                             // sorted insert
      }
    }
    if (bcast64(lk, 15) != ~0ull) break;  // >=16 entries (theorem; always true)
    lk = ~0ull; thr = 0xFFFFFFFFu;        // insurance: exact unseeded rerun
  }

  // clamped index: a sentinel can never reach memory
  const int nj = (int)umin_u((unsigned)(lk & 0xffffffffu), NN - 1u);
  if (lane < KNN) {
    nbr[((size_t)b * NN + i) * KNN + lane] = nj;
  }

  // ---- fused GCN layer 1: x1[i] = relu( ((sum_nbr c + c_i)/17) @ W1 + b1 ) ----
  float r[6];
#pragma unroll
  for (int c = 0; c < 6; ++c) r[c] = 0.f;
  if (lane < KNN) {
    const float* row = cb + (size_t)nj * 6;
    const float2 a = *reinterpret_cast<const float2*>(row);
    const float2 m = *reinterpret_cast<const float2*>(row + 2);
    const float2 q = *reinterpret_cast<const float2*>(row + 4);
    r[0] = a.x; r[1] = a.y; r[2] = m.x; r[3] = m.y; r[4] = q.x; r[5] = q.y;
  }
#pragma unroll
  for (int m = 1; m <= 8; m <<= 1) {
#pragma unroll
    for (int c = 0; c < 6; ++c) r[c] += __shfl_xor(r[c], m);
  }
  const float* self = cb + (size_t)i * 6;
  float agg[6];
#pragma unroll
  for (int c = 0; c < 6; ++c) {
    const float nbs = __uint_as_float(__builtin_amdgcn_readfirstlane(__float_as_uint(r[c])));
    agg[c] = (nbs + self[c]) * (1.0f / 17.0f);
  }
  float acc = b1[lane];
#pragma unroll
  for (int c = 0; c < 6; ++c) acc = fmaf(agg[c], W1[c * 64 + lane], acc);
  x1[((size_t)b * NN + i) * 64 + lane] = fmaxf(acc, 0.f);
}

// ---------------------------------------------------------------------------
// Kernel 2: fused GCN layer 2 + final Linear, register-tiled (R9-proven
// shape, best measured: 32 nodes / 256 threads / 512 blocks, XCD-swizzled).
// ---------------------------------------------------------------------------
__global__ __launch_bounds__(256) void layers_kernel(const float* __restrict__ x1,
                                                     const int* __restrict__ nbr,
                                                     const float* __restrict__ W2,
                                                     const float* __restrict__ b2,
                                                     const float* __restrict__ Wf,
                                                     const float* __restrict__ bf,
                                                     float* __restrict__ out) {
  __shared__ float sA[32][68];    // aggregated x1 (pad 4)
  __shared__ float sB[32][132];   // x2 tile      (pad 4)
  __shared__ int   sN[512];

  const int t   = (int)threadIdx.x;
  const int bid = (int)blockIdx.x;
  // XCD swizzle: XCD k (= bid%8) exclusively processes sample k's 64 tiles
  const int swz = (bid & 7) * 64 + (bid >> 3);
  const int nodeBase = swz * 32;
  const int bs       = nodeBase >> 11;          // sample index (32 | 2048)

  // neighbor lists for 32 nodes (clamped: sentinel can never reach memory)
  sN[t]       = (int)umin_u((unsigned)nbr[(size_t)nodeBase * KNN + t],       NN - 1u);
  sN[t + 256] = (int)umin_u((unsigned)nbr[(size_t)nodeBase * KNN + t + 256], NN - 1u);
  __syncthreads();

  // Phase A: gather-aggregate x1 (thread = node t>>3, dims (t&7)*8 .. +7)
  {
    const int ln = t >> 3;
    const int d8 = (t & 7) * 8;
    const int n  = nodeBase + ln;
    const float* Xb = x1 + (((size_t)bs) << 11) * 64;
    const float* xn = x1 + (size_t)n * 64 + d8;
    float4 s0 = *reinterpret_cast<const float4*>(xn);
    float4 s1 = *reinterpret_cast<const float4*>(xn + 4);
    const int* nb = &sN[ln * 16];
#pragma unroll
    for (int k = 0; k < KNN; ++k) {
      const float* row = Xb + (size_t)nb[k] * 64 + d8;
      const float4 v0 = *reinterpret_cast<const float4*>(row);
      const float4 v1 = *reinterpret_cast<const float4*>(row + 4);
      s0.x += v0.x; s0.y += v0.y; s0.z += v0.z; s0.w += v0.w;
      s1.x += v1.x; s1.y += v1.y; s1.z += v1.z; s1.w += v1.w;
    }
    const float sc = 1.0f / 17.0f;
    sA[ln][d8 + 0] = s0.x * sc; sA[ln][d8 + 1] = s0.y * sc;
    sA[ln][d8 + 2] = s0.z * sc; sA[ln][d8 + 3] = s0.w * sc;
    sA[ln][d8 + 4] = s1.x * sc; sA[ln][d8 + 5] = s1.y * sc;
    sA[ln][d8 + 6] = s1.z * sc; sA[ln][d8 + 7] = s1.w * sc;
  }
  __syncthreads();

  const int ng = (t >> 5) * 4;   // first of 4 nodes
  const int o4 = (t & 31) * 4;   // 4 outputs

  // Phase B: x2 = relu(sA @ W2 + b2) -> sB  (K=64)
  {
    const float4 bv = *reinterpret_cast<const float4*>(b2 + o4);
    float4 acc0 = bv, acc1 = bv, acc2 = bv, acc3 = bv;
#pragma unroll 4
    for (int c = 0; c < 64; ++c) {
      const float4 w = *reinterpret_cast<const float4*>(W2 + (size_t)c * 128 + o4);
      const float a0 = sA[ng + 0][c];
      const float a1 = sA[ng + 1][c];
      const float a2 = sA[ng + 2][c];
      const float a3 = sA[ng + 3][c];
      acc0.x += a0 * w.x; acc0.y += a0 * w.y; acc0.z += a0 * w.z; acc0.w += a0 * w.w;
      acc1.x += a1 * w.x; acc1.y += a1 * w.y; acc1.z += a1 * w.z; acc1.w += a1 * w.w;
      acc2.x += a2 * w.x; acc2.y += a2 * w.y; acc2.z += a2 * w.z; acc2.w += a2 * w.w;
      acc3.x += a3 * w.x; acc3.y += a3 * w.y; acc3.z += a3 * w.z; acc3.w += a3 * w.w;
    }
    sB[ng + 0][o4 + 0] = fmaxf(acc0.x, 0.f); sB[ng + 0][o4 + 1] = fmaxf(acc0.y, 0.f);
    sB[ng + 0][o4 + 2] = fmaxf(acc0.z, 0.f); sB[ng + 0][o4 + 3] = fmaxf(acc0.w, 0.f);
    sB[ng + 1][o4 + 0] = fmaxf(acc1.x, 0.f); sB[ng + 1][o4 + 1] = fmaxf(acc1.y, 0.f);
    sB[ng + 1][o4 + 2] = fmaxf(acc1.z, 0.f); sB[ng + 1][o4 + 3] = fmaxf(acc1.w, 0.f);
    sB[ng + 2][o4 + 0] = fmaxf(acc2.x, 0.f); sB[ng + 2][o4 + 1] = fmaxf(acc2.y, 0.f);
    sB[ng + 2][o4 + 2] = fmaxf(acc2.z, 0.f); sB[ng + 2][o4 + 3] = fmaxf(acc2.w, 0.f);
    sB[ng + 3][o4 + 0] = fmaxf(acc3.x, 0.f); sB[ng + 3][o4 + 1] = fmaxf(acc3.y, 0.f);
    sB[ng + 3][o4 + 2] = fmaxf(acc3.z, 0.f); sB[ng + 3][o4 + 3] = fmaxf(acc3.w, 0.f);
  }
  __syncthreads();

  // Phase C: out = sB @ Wf + bf  (K=128)
  {
    const float4 bv = *reinterpret_cast<const float4*>(bf + o4);
    float4 acc0 = bv, acc1 = bv, acc2 = bv, acc3 = bv;
#pragma unroll 4
    for (int c = 0; c < 128; ++c) {
      const float4 w = *reinterpret_cast<const float4*>(Wf + (size_t)c * 128 + o4);
      const float a0 = sB[ng + 0][c];
      const float a1 = sB[ng + 1][c];
      const float a2 = sB[ng + 2][c];
      const float a3 = sB[ng + 3][c];
      acc0.x += a0 * w.x; acc0.y += a0 * w.y; acc0.z += a0 * w.z; acc0.w += a0 * w.w;
      acc1.x += a1 * w.x; acc1.y += a1 * w.y; acc1.z += a1 * w.z; acc1.w += a1 * w.w;
      acc2.x += a2 * w.x; acc2.y += a2 * w.y; acc2.z += a2 * w.z; acc2.w += a2 * w.w;
      acc3.x += a3 * w.x; acc3.y += a3 * w.y; acc3.z += a3 * w.z; acc3.w += a3 * w.w;
    }
    float* o0 = out + (size_t)(nodeBase + ng) * 128 + o4;
    *reinterpret_cast<float4*>(o0)       = acc0;
    *reinterpret_cast<float4*>(o0 + 128) = acc1;
    *reinterpret_cast<float4*>(o0 + 256) = acc2;
    *reinterpret_cast<float4*>(o0 + 384) = acc3;
  }
}

// ---------------------------------------------------------------------------
extern "C" void kernel_launch(void* const* d_in, const int* in_sizes, int n_in,
                              void* d_out, int out_size, void* d_ws, size_t ws_size,
                              hipStream_t stream) {
  const float* coords = (const float*)d_in[0];
  const float* W1 = (const float*)d_in[1];
  const float* b1 = (const float*)d_in[2];
  const float* W2 = (const float*)d_in[3];
  const float* b2 = (const float*)d_in[4];
  const float* Wf = (const float*)d_in[5];
  const float* bf = (const float*)d_in[6];
  float* out = (float*)d_out;

  char* ws = (char*)d_ws;
  int*   nbr = (int*)ws;                              // 1 MB
  float* x1  = (float*)(ws + (size_t)(1u << 20) * 1); // 4 MB

  // kNN + layer 1: one wave per node, 8 waves/block
  knn_l1_kernel<<<BATCH * (NN / 8), 512, 0, stream>>>(coords, W1, b1, nbr, x1);

  // layer 2 (aggregate + 64->128 + relu) fused with final 128->128 linear
  layers_kernel<<<(BATCH * NN) / 32, 256, 0, stream>>>(x1, nbr, W2, b2, Wf, bf, out);
}